// Round 1
// 109.619 us; speedup vs baseline: 1.0086x; 1.0086x over previous
//
#include <hip/hip_runtime.h>

#define DK 256   // feature dim (K)
#define TT 1024  // T1 = T2
#define NB 16    // batch

typedef __attribute__((ext_vector_type(8))) short bf16x8;
typedef __attribute__((ext_vector_type(4))) float f32x4;

// HW packed fp32->bf16 (RNE). r[15:0]=bf16(lo), r[31:16]=bf16(hi).
// No builtin on gfx950 (guide m240/T12) -> inline asm. Pure-VALU asm, no
// memory ops, so no sched_barrier needed (guide rule 18 applies to ds ops).
__device__ __forceinline__ unsigned int cvt_pk_bf16(float lo, float hi) {
    unsigned int r;
    asm("v_cvt_pk_bf16_f32 %0, %1, %2" : "=v"(r) : "v"(lo), "v"(hi));
    return r;
}

union BF8 { uint4 u; bf16x8 v; };

// ---------------------------------------------------------------------------
// Fully fused: out[b,i,j] = sum_k bf16(x)[b,i,k]*bf16(w3*y)[b,j,k]
//                           + (x.w1)[b,i] + (y.w2)[b,j]
//
// R6 changes vs R5 (rocprof: fused_kernel < 42 us; timed region carries
// ~86 us of harness fills at HBM ceiling; kernel residual ~24 us, floor ~12):
//  * fp32->bf16 via v_cvt_pk_bf16_f32 (2 elems/instr, pre-packed) instead of
//    manual bit-RNE f2bf (~4 VALU ops/elem + repack). ~200M conversions/launch
//    (x re-converted 8x, y 4x) -> ~10 us of VALU removed from the kernel.
//  * w2/w3 loads hoisted out of the stage loop (it-invariant: c = tid&31).
//  * Everything else (tiling, XOR swizzle, XCD-locality id decode, single
//    barrier, store pattern) identical to the verified R5 structure.
// ---------------------------------------------------------------------------
__global__ __launch_bounds__(512, 4) void fused_kernel(
    const float* __restrict__ x, const float* __restrict__ y,
    const float* __restrict__ WS, float* __restrict__ out)
{
    __shared__ unsigned short Bs[128 * DK];   // 64 KB
    __shared__ float tys[128];

    const int tid  = threadIdx.x;
    const int lane = tid & 63;
    const int w    = tid >> 6;                // wave 0..7

    // XCD-locality decode: id%8 constant across the jt group and the is group
    const int id = blockIdx.x;                // 0..511
    const int b  = id & 15;                   // batch
    const int is = (id >> 4) & 3;             // i slice (0..3), 256 rows
    const int jt = id >> 6;                   // j tile (0..7), 128 cols

    // ---- 1. stage B = bf16(w3*y) (XOR-swizzled), ty = y.w2
    {
        const float* gY0 = y + ((size_t)b * TT + jt * 128) * DK;
        const int c = tid & 31;               // 16B chunk within row (it-invariant)
        const float* w3p = WS + 2 * DK + c * 8;
        const float* w2p = WS + DK + c * 8;
        const float4 wa = *(const float4*)(w3p);
        const float4 wb = *(const float4*)(w3p + 4);
        const float4 va = *(const float4*)(w2p);
        const float4 vb = *(const float4*)(w2p + 4);
        #pragma unroll
        for (int it = 0; it < 8; ++it) {
            const int j = it * 16 + (tid >> 5);   // local row 0..127
            const float* gY = gY0 + (size_t)j * DK + c * 8;
            const float4 ya = *(const float4*)(gY);
            const float4 yb = *(const float4*)(gY + 4);
            float p = ya.x * va.x + ya.y * va.y + ya.z * va.z + ya.w * va.w
                    + yb.x * vb.x + yb.y * vb.y + yb.z * vb.z + yb.w * vb.w;
            uint4 o;
            o.x = cvt_pk_bf16(ya.x * wa.x, ya.y * wa.y);
            o.y = cvt_pk_bf16(ya.z * wa.z, ya.w * wa.w);
            o.z = cvt_pk_bf16(yb.x * wb.x, yb.y * wb.y);
            o.w = cvt_pk_bf16(yb.z * wb.z, yb.w * wb.w);
            const int slot = c ^ (j & 7);
            *(uint4*)(Bs + j * DK + slot * 8) = o;
            // reduce p across the 32 lanes sharing row j
            p += __shfl_xor(p, 1);
            p += __shfl_xor(p, 2);
            p += __shfl_xor(p, 4);
            p += __shfl_xor(p, 8);
            p += __shfl_xor(p, 16);
            if ((tid & 31) == 0) tys[j] = p;
        }
    }
    __syncthreads();                          // the ONLY barrier

    // ---- 2. barrier-free K-loop: wave owns 32 i-rows
    const int mfr  = lane & 15;
    const int quad = lane >> 4;
    const int i0   = is * 256 + w * 32;
    const float* gA = x + ((size_t)b * TT + i0) * DK;

    f32x4 acc[2][8];
    #pragma unroll
    for (int it = 0; it < 2; ++it)
        #pragma unroll
        for (int n = 0; n < 8; ++n)
            acc[it][n] = (f32x4){0.f, 0.f, 0.f, 0.f};
    float txp[2] = {0.f, 0.f};

    #pragma unroll
    for (int ks = 0; ks < 8; ++ks) {
        const float* w1p = WS + ks * 32 + quad * 8;
        const float4 w1a = *(const float4*)(w1p);
        const float4 w1b = *(const float4*)(w1p + 4);
        bf16x8 av[2];
        #pragma unroll
        for (int it = 0; it < 2; ++it) {
            const float* rp = gA + (size_t)(it * 16 + mfr) * DK
                              + ks * 32 + quad * 8;
            const float4 xa = *(const float4*)rp;
            const float4 xb = *(const float4*)(rp + 4);
            txp[it] += xa.x * w1a.x + xa.y * w1a.y + xa.z * w1a.z + xa.w * w1a.w
                     + xb.x * w1b.x + xb.y * w1b.y + xb.z * w1b.z + xb.w * w1b.w;
            BF8 cv;
            cv.u.x = cvt_pk_bf16(xa.x, xa.y);
            cv.u.y = cvt_pk_bf16(xa.z, xa.w);
            cv.u.z = cvt_pk_bf16(xb.x, xb.y);
            cv.u.w = cvt_pk_bf16(xb.z, xb.w);
            av[it] = cv.v;
        }
        #pragma unroll
        for (int n = 0; n < 8; ++n) {
            const int j    = n * 16 + mfr;
            const int slot = (ks * 4 + quad) ^ (j & 7);
            const bf16x8 bv = *(const bf16x8*)(Bs + j * DK + slot * 8);
            #pragma unroll
            for (int it = 0; it < 2; ++it)
                acc[it][n] = __builtin_amdgcn_mfma_f32_16x16x32_bf16(
                    av[it], bv, acc[it][n], 0, 0, 0);
        }
    }

    // ---- 3. epilogue: tx quad-reduction, + tx[i] + ty[j], fp32 stores
    #pragma unroll
    for (int it = 0; it < 2; ++it) {
        txp[it] += __shfl_xor(txp[it], 16);
        txp[it] += __shfl_xor(txp[it], 32);
        // lane now holds full tx for row i0 + it*16 + mfr
    }

    float tyv[8];
    #pragma unroll
    for (int n = 0; n < 8; ++n)
        tyv[n] = tys[n * 16 + mfr];

    float* outB = out + ((size_t)b << 20) + (size_t)i0 * TT + jt * 128;
    #pragma unroll
    for (int it = 0; it < 2; ++it) {
        #pragma unroll
        for (int r = 0; r < 4; ++r) {
            const int row = it * 16 + quad * 4 + r;
            // tx for this row lives at lanes with mfr == quad*4+r (any quad)
            const float trow = __shfl(txp[it], (lane & 48) | (quad * 4 + r));
            #pragma unroll
            for (int n = 0; n < 8; ++n)
                outB[(size_t)row * TT + n * 16 + mfr] =
                    acc[it][n][r] + trow + tyv[n];
        }
    }
}

extern "C" void kernel_launch(void* const* d_in, const int* in_sizes, int n_in,
                              void* d_out, int out_size, void* d_ws, size_t ws_size,
                              hipStream_t stream)
{
    const float* x  = (const float*)d_in[0];
    const float* y  = (const float*)d_in[1];
    const float* WS = (const float*)d_in[2];
    float* out = (float*)d_out;
    (void)d_ws; (void)ws_size;   // no workspace needed — fully fused

    fused_kernel<<<dim3(512), dim3(512), 0, stream>>>(x, y, WS, out);
}